// Round 1
// baseline (841.430 us; speedup 1.0000x reference)
//
#include <hip/hip_runtime.h>
#include <math.h>

// Attention_10230612099272: B=2,S=2048,H=2048,nh=16,hd=128, fp32 in/out,
// bf16 MFMA internally (threshold 4.47e-3 allows it).
// Pipeline: cvt X -> bf16; per-W transpose->bf16 (n,k); GEMM(QKV, fused
// bias+RoPE, V transposed); flash attention; GEMM(out, fp32 + bias).

typedef __bf16 bf16;
typedef __attribute__((ext_vector_type(8))) __bf16 bf16x8;
typedef __attribute__((ext_vector_type(4))) __bf16 bf16x4;
typedef __attribute__((ext_vector_type(4))) float f32x4;

#define S_LEN 2048
#define NHEAD 16
#define HD 128

__device__ __forceinline__ void async16(const void* g, void* l) {
    __builtin_amdgcn_global_load_lds(
        (const __attribute__((address_space(1))) void*)g,
        (__attribute__((address_space(3))) void*)l, 16, 0, 0);
}

__device__ __forceinline__ f32x4 mfma16(bf16x8 a, bf16x8 b, f32x4 c) {
    return __builtin_amdgcn_mfma_f32_16x16x32_bf16(a, b, c, 0, 0, 0);
}

// ---------------- fp32 -> bf16 elementwise ----------------
__global__ __launch_bounds__(256) void cvt_f32_bf16(const float* __restrict__ x,
                                                    bf16* __restrict__ y, int n) {
    int i = (blockIdx.x * 256 + threadIdx.x) * 4;
    if (i + 3 < n) {
        const float4 v = *(const float4*)(x + i);
        bf16x4 o;
        o[0] = (bf16)v.x; o[1] = (bf16)v.y; o[2] = (bf16)v.z; o[3] = (bf16)v.w;
        *(bf16x4*)(y + i) = o;
    }
}

// ---------------- W (k,n) fp32 -> Wt (n,k) bf16 ----------------
__global__ __launch_bounds__(256) void transpose_cvt(const float* __restrict__ W,
                                                     bf16* __restrict__ Wt,
                                                     int Kd, int Nd) {
    __shared__ float tile[32][33];
    const int tx = threadIdx.x & 31, ty = threadIdx.x >> 5;
    const int bn = blockIdx.x * 32, bk = blockIdx.y * 32;
#pragma unroll
    for (int r = 0; r < 32; r += 8)
        tile[ty + r][tx] = W[(size_t)(bk + ty + r) * Nd + bn + tx];
    __syncthreads();
#pragma unroll
    for (int r = 0; r < 32; r += 8)
        Wt[(size_t)(bn + ty + r) * Kd + bk + tx] = (bf16)tile[tx][ty + r];
}

// ---------------- GEMM C[m,n] = A[m,:] . Bt[n,:] + bias -------------
// MODE 0: Q (bias+RoPE, *1/sqrt(hd), -> [b,h,s,d])
// MODE 1: K (bias+RoPE, -> [b,h,s,d])
// MODE 2: V (bias, -> Vt [b,h,d,s])
// MODE 3: OUT (bias, fp32 row-major [m,n])
template <int MODE>
__global__ __launch_bounds__(256, 2)
void gemm_bt(const bf16* __restrict__ A, const bf16* __restrict__ Bt,
             const float* __restrict__ bias, bf16* __restrict__ outB,
             float* __restrict__ outF, int M, int N, int K) {
    __shared__ __align__(16) bf16 As[128 * 64];
    __shared__ __align__(16) bf16 Bs[128 * 64];
    const int t = threadIdx.x;
    const int w = t >> 6, l = t & 63;
    const int lr = l & 15, lq = l >> 4;
    const int m0 = blockIdx.y * 128, n0 = blockIdx.x * 128;
    const int wm = (w >> 1) * 64, wn = (w & 1) * 64;

    f32x4 acc[4][4];
    const f32x4 fz = {0.f, 0.f, 0.f, 0.f};
#pragma unroll
    for (int i = 0; i < 4; ++i)
#pragma unroll
        for (int j = 0; j < 4; ++j) acc[i][j] = fz;

    for (int k0 = 0; k0 < K; k0 += 64) {
        __syncthreads();
#pragma unroll
        for (int c = 0; c < 4; ++c) {
            const int chunk = c * 256 + t;
            const int row = chunk >> 3, kc = (chunk & 7) << 3;
            async16(A + (size_t)(m0 + row) * K + k0 + kc, &As[chunk * 8]);
            async16(Bt + (size_t)(n0 + row) * K + k0 + kc, &Bs[chunk * 8]);
        }
        __syncthreads();
#pragma unroll
        for (int s = 0; s < 2; ++s) {
            bf16x8 af[4], bfr[4];
#pragma unroll
            for (int i = 0; i < 4; ++i)
                af[i] = *(const bf16x8*)&As[(wm + i * 16 + lr) * 64 + s * 32 + lq * 8];
#pragma unroll
            for (int j = 0; j < 4; ++j)
                bfr[j] = *(const bf16x8*)&Bs[(wn + j * 16 + lr) * 64 + s * 32 + lq * 8];
#pragma unroll
            for (int i = 0; i < 4; ++i)
#pragma unroll
                for (int j = 0; j < 4; ++j)
                    acc[i][j] = mfma16(af[i], bfr[j], acc[i][j]);
        }
    }

    // epilogue: C/D layout col=lane&15, row=(lane>>4)*4+reg (m89-verified)
    if (MODE == 3) {
#pragma unroll
        for (int i = 0; i < 4; ++i) {
            const int rg0 = m0 + wm + i * 16 + lq * 4;
#pragma unroll
            for (int j = 0; j < 4; ++j) {
                const int cg = n0 + wn + j * 16 + lr;
                const float bv = bias[cg];
#pragma unroll
                for (int r = 0; r < 4; ++r)
                    outF[(size_t)(rg0 + r) * N + cg] = acc[i][j][r] + bv;
            }
        }
    } else if (MODE == 2) {
#pragma unroll
        for (int i = 0; i < 4; ++i) {
            const int rg0 = m0 + wm + i * 16 + lq * 4;
#pragma unroll
            for (int j = 0; j < 4; ++j) {
                const int cg = n0 + wn + j * 16 + lr;
                const float bv = bias[cg];
                const int h = cg >> 7, d = cg & 127;
#pragma unroll
                for (int r = 0; r < 4; ++r) {
                    const int rg = rg0 + r;
                    const int b = rg >> 11, s = rg & 2047;
                    outB[((size_t)((b << 4) + h) * HD + d) * S_LEN + s] =
                        (bf16)(acc[i][j][r] + bv);
                }
            }
        }
    } else {
        // RoPE: pairs (2j,2j+1) are adjacent columns => adjacent lanes (xor 1)
#pragma unroll
        for (int i = 0; i < 4; ++i) {
            const int rg0 = m0 + wm + i * 16 + lq * 4;
#pragma unroll
            for (int j = 0; j < 4; ++j) {
                const int cg = n0 + wn + j * 16 + lr;
                const float bv = bias[cg];
                const int h = cg >> 7, d = cg & 127;
                // inv_freq = 10000^(-(d/2)/64) = 2^(-(d/2)*log2(1e4)/64)
                const float invf = exp2f(-0.20762050593046013f * (float)(d >> 1));
#pragma unroll
                for (int r = 0; r < 4; ++r) {
                    const int rg = rg0 + r;
                    const int b = rg >> 11, s = rg & 2047;
                    float v = acc[i][j][r] + bv;
                    float p = __shfl_xor(v, 1);
                    float sn, cs;
                    sincosf((float)s * invf, &sn, &cs);
                    float o = (d & 1) ? (v * cs + p * sn) : (v * cs - p * sn);
                    if (MODE == 0) o *= 0.08838834764831843f;  // 1/sqrt(128)
                    outB[((size_t)((b << 4) + h) * S_LEN + s) * HD + d] = (bf16)o;
                }
            }
        }
    }
}

// ---------------- flash attention ----------------
// grid (qt=16, bh=32), 256 thr. Q,K: [bh][s][128] bf16; Vt: [bh][128][s] bf16.
// AO: [b*S+s][h*128+d] bf16 row-major (feeds final GEMM).
__global__ __launch_bounds__(256, 2)
void attn_fwd(const bf16* __restrict__ Q, const bf16* __restrict__ K,
              const bf16* __restrict__ Vt, bf16* __restrict__ AO) {
    __shared__ __align__(16) bf16 Ks[128 * 128];  // doubles as P after QK^T
    __shared__ __align__(16) bf16 Vs[128 * 128];
    const int t = threadIdx.x;
    const int w = t >> 6, l = t & 63;
    const int lr = l & 15, lq = l >> 4;
    const int qt = blockIdx.x, bh = blockIdx.y;
    const int b = bh >> 4, h = bh & 15;

    const bf16* Qp = Q + (size_t)bh * S_LEN * HD;
    const bf16* Kp = K + (size_t)bh * S_LEN * HD;
    const bf16* Vp = Vt + (size_t)bh * HD * S_LEN;

    // Q A-fragments in registers: A[m=lane&15][k=quad*8+j] (m120-verified)
    bf16x8 qf[2][4];
#pragma unroll
    for (int i = 0; i < 2; ++i)
#pragma unroll
        for (int s = 0; s < 4; ++s)
            qf[i][s] = *(const bf16x8*)&Qp[(size_t)(qt * 128 + w * 32 + i * 16 + lr) * HD +
                                           s * 32 + lq * 8];

    f32x4 O[2][8];
    const f32x4 fz = {0.f, 0.f, 0.f, 0.f};
#pragma unroll
    for (int i = 0; i < 2; ++i)
#pragma unroll
        for (int jd = 0; jd < 8; ++jd) O[i][jd] = fz;
    float mst[2][4], lst[2][4];
#pragma unroll
    for (int i = 0; i < 2; ++i)
#pragma unroll
        for (int r = 0; r < 4; ++r) { mst[i][r] = -INFINITY; lst[i][r] = 0.f; }

    for (int kt = 0; kt < 16; ++kt) {
        __syncthreads();  // prior-iter LDS reads done before restaging
#pragma unroll
        for (int c = 0; c < 8; ++c) {
            const int chunk = c * 256 + t;
            const int row = chunk >> 4, co = (chunk & 15) << 3;
            async16(&Kp[(size_t)(kt * 128 + row) * HD + co], &Ks[chunk * 8]);
            async16(&Vp[(size_t)row * S_LEN + kt * 128 + co], &Vs[chunk * 8]);
        }
        __syncthreads();

        // S = Q K^T  (scale folded into Q)
        f32x4 Sc[2][8];
#pragma unroll
        for (int i = 0; i < 2; ++i)
#pragma unroll
            for (int j = 0; j < 8; ++j) Sc[i][j] = fz;
#pragma unroll
        for (int s = 0; s < 4; ++s) {
            bf16x8 kf[8];
#pragma unroll
            for (int j = 0; j < 8; ++j)
                kf[j] = *(const bf16x8*)&Ks[(j * 16 + lr) * 128 + s * 32 + lq * 8];
#pragma unroll
            for (int i = 0; i < 2; ++i)
#pragma unroll
                for (int j = 0; j < 8; ++j)
                    Sc[i][j] = mfma16(qf[i][s], kf[j], Sc[i][j]);
        }
        __syncthreads();  // all waves done reading Ks before P overwrites it

        bf16* Ps = Ks;
#pragma unroll
        for (int i = 0; i < 2; ++i) {
            f32x4 rm = Sc[i][0];
#pragma unroll
            for (int j = 1; j < 8; ++j)
#pragma unroll
                for (int r = 0; r < 4; ++r) rm[r] = fmaxf(rm[r], Sc[i][j][r]);
#pragma unroll
            for (int mask = 1; mask < 16; mask <<= 1)
#pragma unroll
                for (int r = 0; r < 4; ++r)
                    rm[r] = fmaxf(rm[r], __shfl_xor(rm[r], mask));
            float alpha[4];
#pragma unroll
            for (int r = 0; r < 4; ++r) {
                const float mn = fmaxf(mst[i][r], rm[r]);
                alpha[r] = __expf(mst[i][r] - mn);
                mst[i][r] = mn;
                lst[i][r] *= alpha[r];
            }
#pragma unroll
            for (int jd = 0; jd < 8; ++jd)
#pragma unroll
                for (int r = 0; r < 4; ++r) O[i][jd][r] *= alpha[r];
            f32x4 rs = fz;
#pragma unroll
            for (int j = 0; j < 8; ++j)
#pragma unroll
                for (int r = 0; r < 4; ++r) {
                    const float p = __expf(Sc[i][j][r] - mst[i][r]);
                    rs[r] += p;
                    Ps[(w * 32 + i * 16 + lq * 4 + r) * 128 + j * 16 + lr] = (bf16)p;
                }
#pragma unroll
            for (int mask = 1; mask < 16; mask <<= 1)
#pragma unroll
                for (int r = 0; r < 4; ++r) rs[r] += __shfl_xor(rs[r], mask);
#pragma unroll
            for (int r = 0; r < 4; ++r) lst[i][r] += rs[r];
        }
        __syncthreads();  // P visible

        // O += P V  (B operand from Vt tile: B[n=d][k=kk])
#pragma unroll
        for (int s = 0; s < 4; ++s) {
            bf16x8 pf[2], vf[8];
#pragma unroll
            for (int i = 0; i < 2; ++i)
                pf[i] = *(const bf16x8*)&Ps[(w * 32 + i * 16 + lr) * 128 + s * 32 + lq * 8];
#pragma unroll
            for (int jd = 0; jd < 8; ++jd)
                vf[jd] = *(const bf16x8*)&Vs[(jd * 16 + lr) * 128 + s * 32 + lq * 8];
#pragma unroll
            for (int i = 0; i < 2; ++i)
#pragma unroll
                for (int jd = 0; jd < 8; ++jd)
                    O[i][jd] = mfma16(pf[i], vf[jd], O[i][jd]);
        }
    }

#pragma unroll
    for (int i = 0; i < 2; ++i)
#pragma unroll
        for (int jd = 0; jd < 8; ++jd)
#pragma unroll
            for (int r = 0; r < 4; ++r) {
                const int srow = qt * 128 + w * 32 + i * 16 + lq * 4 + r;
                const float v = O[i][jd][r] / lst[i][r];
                AO[(size_t)(b * S_LEN + srow) * 2048 + h * HD + jd * 16 + lr] = (bf16)v;
            }
}

extern "C" void kernel_launch(void* const* d_in, const int* in_sizes, int n_in,
                              void* d_out, int out_size, void* d_ws, size_t ws_size,
                              hipStream_t stream) {
    const float* hs = (const float*)d_in[0];
    const float* Wq = (const float*)d_in[1];
    const float* bq = (const float*)d_in[2];
    const float* Wk = (const float*)d_in[3];
    const float* bk = (const float*)d_in[4];
    const float* Wv = (const float*)d_in[5];
    const float* bv = (const float*)d_in[6];
    const float* Wo = (const float*)d_in[7];
    const float* bo = (const float*)d_in[8];
    float* out = (float*)d_out;

    // workspace: Xb 16MB | Wt 8MB | Q 16MB | K 16MB | Vt 16MB  (72MB total)
    char* ws = (char*)d_ws;
    bf16* Xb = (bf16*)ws;
    bf16* Wt = (bf16*)(ws + (size_t)16777216);
    bf16* Qb = (bf16*)(ws + (size_t)25165824);
    bf16* Kb = (bf16*)(ws + (size_t)41943040);
    bf16* Vb = (bf16*)(ws + (size_t)58720256);
    bf16* AO = Xb;  // X no longer needed after the V projection

    const dim3 tg(64, 64);   // transpose grid
    const dim3 gg(16, 32);   // gemm grid (N/128, M/128)

    cvt_f32_bf16<<<8192, 256, 0, stream>>>(hs, Xb, 8388608);
    transpose_cvt<<<tg, 256, 0, stream>>>(Wq, Wt, 2048, 2048);
    gemm_bt<0><<<gg, 256, 0, stream>>>(Xb, Wt, bq, Qb, nullptr, 4096, 2048, 2048);
    transpose_cvt<<<tg, 256, 0, stream>>>(Wk, Wt, 2048, 2048);
    gemm_bt<1><<<gg, 256, 0, stream>>>(Xb, Wt, bk, Kb, nullptr, 4096, 2048, 2048);
    transpose_cvt<<<tg, 256, 0, stream>>>(Wv, Wt, 2048, 2048);
    gemm_bt<2><<<gg, 256, 0, stream>>>(Xb, Wt, bv, Vb, nullptr, 4096, 2048, 2048);
    attn_fwd<<<dim3(16, 32), 256, 0, stream>>>(Qb, Kb, Vb, AO);
    transpose_cvt<<<tg, 256, 0, stream>>>(Wo, Wt, 2048, 2048);
    gemm_bt<3><<<gg, 256, 0, stream>>>(AO, Wt, bo, nullptr, out, 4096, 2048, 2048);
}